// Round 8
// baseline (363.252 us; speedup 1.0000x reference)
//
#include <hip/hip_runtime.h>

// Problem: B=2, S=2048, DIM=1024, H=16, DH=64. I/O fp32; internals bf16 MFMA.
#define Bn   2
#define Sn   2048
#define DIMn 1024
#define Hn   16
#define DHn  64

typedef unsigned short u16;
typedef unsigned int   u32;

typedef __attribute__((ext_vector_type(8))) __bf16 bf16x8;
typedef __attribute__((ext_vector_type(8))) float  f32x8v;
typedef __attribute__((ext_vector_type(4))) float  f32x4;

__device__ __forceinline__ u16 f2bf(float f) {
    union { float f; u32 u; } v; v.f = f;
    u32 r = v.u + 0x7fffu + ((v.u >> 16) & 1u);  // RNE
    return (u16)(r >> 16);
}
__device__ __forceinline__ bf16x8 ldfrag(const u16* p) {
    union { uint4 u; bf16x8 v; } x;
    x.u = *(const uint4*)p;
    return x.v;
}
__device__ __forceinline__ uint4 pack8(const u16 h[8]) {
    uint4 r;
    r.x = (u32)h[0] | ((u32)h[1] << 16);
    r.y = (u32)h[2] | ((u32)h[3] << 16);
    r.z = (u32)h[4] | ((u32)h[5] << 16);
    r.w = (u32)h[6] | ((u32)h[7] << 16);
    return r;
}
__device__ __forceinline__ uint4 cvt8(const f32x8v& f) {
    union { bf16x8 v; uint4 u; } x;
    x.v = __builtin_convertvector(f, bf16x8);
    return x.u;
}

// ---------------------------------------------------------------------------
// Prep: transpose+convert the 4 fp32 weights [k][n] -> bf16 Wt[n][k].
// grid (16,16,4), block 256. Tile 64x64 via LDS.
// ---------------------------------------------------------------------------
__global__ __launch_bounds__(256) void prep_weights(
    const float* __restrict__ Wq, const float* __restrict__ Wk,
    const float* __restrict__ Wv, const float* __restrict__ Wf,
    u16* __restrict__ Wt)
{
    __shared__ __align__(16) float tile[64][68];
    const float* W = (blockIdx.z == 0) ? Wq : (blockIdx.z == 1) ? Wk
                   : (blockIdx.z == 2) ? Wv : Wf;
    u16* out = Wt + (size_t)blockIdx.z * DIMn * DIMn;
    const int t = threadIdx.x;
    const int n0 = blockIdx.x * 64, k0 = blockIdx.y * 64;
    const int rr = t >> 4, cc = (t & 15) * 4;
#pragma unroll
    for (int i = 0; i < 4; i++)
        *(float4*)&tile[rr + 16 * i][cc] =
            *(const float4*)(W + (size_t)(k0 + rr + 16 * i) * DIMn + n0 + cc);
    __syncthreads();
#pragma unroll
    for (int e = 0; e < 2; e++) {
        const int ci = 2 * t + e;
        const int n = ci >> 3, kc = ci & 7;
        u16 h[8];
#pragma unroll
        for (int j = 0; j < 8; j++) h[j] = f2bf(tile[kc * 8 + j][n]);
        *(uint4*)(out + (size_t)(n0 + n) * DIMn + k0 + kc * 8) = pack8(h);
    }
}

// ---------------------------------------------------------------------------
// Fused QKV projection GEMM, XCD-swizzled, packed epilogue.
// Flat grid 768 = 8 XCD x (3 z x 4 yi x 8 x). Each XCD owns 4 y-slabs of A
// and streams all 3 weights. C = A(fp32) @ W + bias; z<2 -> bf16 [b,h,s,d];
// z==2 -> bf16 [b,h,d,s]. Epilogue transposes via LDS, emits 16B stores.
// ---------------------------------------------------------------------------
__global__ __launch_bounds__(256) void gemm_qkv(
    const float* __restrict__ Aq, const float* __restrict__ Ak,
    const float* __restrict__ Av, const u16* __restrict__ Wt,
    const float* __restrict__ bqp, const float* __restrict__ bkp,
    const float* __restrict__ bvp, u16* __restrict__ Qw,
    u16* __restrict__ Kw, u16* __restrict__ VwT)
{
    __shared__ union {
        struct { __align__(16) u16 As[128][40]; __align__(16) u16 Bs[128][40]; } s;
        __align__(16) u16 Ep[32][144];  // epilogue staging (9216 B)
    } L;

    // ---- XCD-aware swizzle: f = xcd + 8*(x + 8*(yi + 4*z)) ----
    const int f = blockIdx.x;
    const int xcd = f & 7;
    const int q = f >> 3;           // 0..95
    const int z = q >> 5;           // weight/input select, outer per XCD
    const int rem = q & 31;
    const int yi = rem >> 3, x = rem & 7;
    const int y = xcd * 4 + yi;
    const int m0 = y * 128, n0 = x * 128;

    const float* A    = (z == 0) ? Aq  : (z == 1) ? Ak  : Av;
    const float* bias = (z == 0) ? bqp : (z == 1) ? bkp : bvp;
    const u16* Bt = Wt + (size_t)z * DIMn * DIMn;

    const int t = threadIdx.x;
    const int lane = t & 63, wave = t >> 6;
    const int quad = lane >> 4, l15 = lane & 15;
    const int wm = wave >> 1, wn = wave & 1;

    f32x4 acc[4][4];
#pragma unroll
    for (int i = 0; i < 4; i++)
#pragma unroll
        for (int j = 0; j < 4; j++) acc[i][j] = (f32x4){0.f, 0.f, 0.f, 0.f};

    for (int k0 = 0; k0 < DIMn; k0 += 32) {
        union { float4 f4[2]; f32x8v v8; } au[2];
        uint4 bvv[2];
#pragma unroll
        for (int e = 0; e < 2; e++) {
            const int ci = 2 * t + e, row = ci >> 2, kc = ci & 3;
            const float* src = A + (size_t)(m0 + row) * DIMn + k0 + kc * 8;
            au[e].f4[0] = *(const float4*)src;
            au[e].f4[1] = *(const float4*)(src + 4);
            bvv[e]      = *(const uint4*)(Bt + (size_t)(n0 + row) * DIMn + k0 + kc * 8);
        }
        __syncthreads();  // previous iteration's frag reads complete
#pragma unroll
        for (int e = 0; e < 2; e++) {
            const int ci = 2 * t + e, row = ci >> 2, kc = ci & 3;
            *(uint4*)&L.s.As[row][kc * 8] = cvt8(au[e].v8);
            *(uint4*)&L.s.Bs[row][kc * 8] = bvv[e];
        }
        __syncthreads();
        bf16x8 a[4], b[4];
#pragma unroll
        for (int i = 0; i < 4; i++) a[i] = ldfrag(&L.s.As[wm * 64 + i * 16 + l15][quad * 8]);
#pragma unroll
        for (int j = 0; j < 4; j++) b[j] = ldfrag(&L.s.Bs[wn * 64 + j * 16 + l15][quad * 8]);
#pragma unroll
        for (int i = 0; i < 4; i++)
#pragma unroll
            for (int j = 0; j < 4; j++)
                acc[i][j] = __builtin_amdgcn_mfma_f32_16x16x32_bf16(a[i], b[j], acc[i][j], 0, 0, 0);
    }

    float bv[4];
#pragma unroll
    for (int j = 0; j < 4; j++) bv[j] = bias[n0 + wn * 64 + j * 16 + l15];

    const int bb = y >> 4;  // block-uniform batch

    if (z < 2) {
        // ---- split [b,h,s,d]: phase over i (32 m-rows x 128 n per phase) ----
        u16* out = (z == 0) ? Qw : Kw;
#pragma unroll
        for (int i = 0; i < 4; i++) {
            __syncthreads();
#pragma unroll
            for (int j = 0; j < 4; j++)
#pragma unroll
                for (int r = 0; r < 4; r++)
                    L.Ep[wm * 16 + quad * 4 + r][wn * 64 + j * 16 + l15] =
                        f2bf(acc[i][j][r] + bv[j]);
            __syncthreads();
            // read-out: 512 chunks of 8 u16 (2 per thread) = 32x128 tile
#pragma unroll
            for (int e = 0; e < 2; e++) {
                const int ci = t + 256 * e;
                const int row = ci >> 4, c = ci & 15;
                const uint4 v = *(const uint4*)&L.Ep[row][c * 8];
                const int m = m0 + (row >> 4) * 64 + i * 16 + (row & 15);
                const int ss = m & 2047;
                const int n = n0 + c * 8;
                const int hh = n >> 6, dd = n & 63;
                *(uint4*)(out + ((size_t)(bb * Hn + hh) * Sn + ss) * DHn + dd) = v;
            }
        }
    } else {
        // ---- transposed [b,h,d,s]: phase over j (32 n-rows x 128 m) ----
#pragma unroll
        for (int j = 0; j < 4; j++) {
            __syncthreads();
#pragma unroll
            for (int i = 0; i < 4; i++) {
                u16 h4[4];
#pragma unroll
                for (int r = 0; r < 4; r++) h4[r] = f2bf(acc[i][j][r] + bv[j]);
                uint2 pk;
                pk.x = (u32)h4[0] | ((u32)h4[1] << 16);
                pk.y = (u32)h4[2] | ((u32)h4[3] << 16);
                *(uint2*)&L.Ep[wn * 16 + l15][wm * 64 + i * 16 + quad * 4] = pk;
            }
            __syncthreads();
#pragma unroll
            for (int e = 0; e < 2; e++) {
                const int ci = t + 256 * e;
                const int row = ci >> 4, c = ci & 15;
                const uint4 v = *(const uint4*)&L.Ep[row][c * 8];
                const int n = n0 + (row >> 4) * 64 + j * 16 + (row & 15);
                const int hh = n >> 6, dd = n & 63;
                const int ss = (m0 & 2047) + c * 8;
                *(uint4*)(VwT + ((size_t)(bb * Hn + hh) * DHn + dd) * Sn + ss) = v;
            }
        }
    }
}

// ---------------------------------------------------------------------------
// MFMA GEMM (final): C = A(bf16, split [b,h,s,d]) @ W + bias -> fp32 [m][n].
// XCD-swizzled flat grid 256.
// ---------------------------------------------------------------------------
__global__ __launch_bounds__(256) void gemm_final(
    const u16* __restrict__ A, const u16* __restrict__ Bt,
    const float* __restrict__ bias, float* __restrict__ out)
{
    __shared__ __align__(16) u16 As[128][40];
    __shared__ __align__(16) u16 Bs[128][40];

    const int f = blockIdx.x;
    const int xcd = f & 7, q = f >> 3;     // q 0..31
    const int y = xcd * 4 + (q >> 3), x = q & 7;
    const int m0 = y * 128, n0 = x * 128;

    const int t = threadIdx.x;
    const int lane = t & 63, wave = t >> 6;
    const int quad = lane >> 4, l15 = lane & 15;
    const int wm = wave >> 1, wn = wave & 1;

    f32x4 acc[4][4];
#pragma unroll
    for (int i = 0; i < 4; i++)
#pragma unroll
        for (int j = 0; j < 4; j++) acc[i][j] = (f32x4){0.f, 0.f, 0.f, 0.f};

    for (int k0 = 0; k0 < DIMn; k0 += 32) {
        const int hh = k0 >> 6;            // head for this k-slab
        uint4 avv[2], bvv[2];
#pragma unroll
        for (int e = 0; e < 2; e++) {
            const int ci = 2 * t + e, row = ci >> 2, kc = ci & 3;
            const int m = m0 + row, bb = m >> 11, ss = m & 2047;
            const int d0 = (k0 & 63) + kc * 8;
            avv[e] = *(const uint4*)(A + ((size_t)(bb * Hn + hh) * Sn + ss) * DHn + d0);
            bvv[e] = *(const uint4*)(Bt + (size_t)(n0 + row) * DIMn + k0 + kc * 8);
        }
        __syncthreads();
#pragma unroll
        for (int e = 0; e < 2; e++) {
            const int ci = 2 * t + e, row = ci >> 2, kc = ci & 3;
            *(uint4*)&As[row][kc * 8] = avv[e];
            *(uint4*)&Bs[row][kc * 8] = bvv[e];
        }
        __syncthreads();
        bf16x8 a[4], b[4];
#pragma unroll
        for (int i = 0; i < 4; i++) a[i] = ldfrag(&As[wm * 64 + i * 16 + l15][quad * 8]);
#pragma unroll
        for (int j = 0; j < 4; j++) b[j] = ldfrag(&Bs[wn * 64 + j * 16 + l15][quad * 8]);
#pragma unroll
        for (int i = 0; i < 4; i++)
#pragma unroll
            for (int j = 0; j < 4; j++)
                acc[i][j] = __builtin_amdgcn_mfma_f32_16x16x32_bf16(a[i], b[j], acc[i][j], 0, 0, 0);
    }

    float bv[4];
#pragma unroll
    for (int j = 0; j < 4; j++) bv[j] = bias[n0 + wn * 64 + j * 16 + l15];

#pragma unroll
    for (int i = 0; i < 4; i++)
#pragma unroll
        for (int j = 0; j < 4; j++) {
            const int n = n0 + wn * 64 + j * 16 + l15;
#pragma unroll
            for (int r = 0; r < 4; r++) {
                const int m = m0 + wm * 64 + i * 16 + quad * 4 + r;
                out[(size_t)m * DIMn + n] = acc[i][j][r] + bv[j];
            }
        }
}

// ---------------------------------------------------------------------------
// MFMA flash attention (no max-tracking; scores O(1), no all-masked rows).
// XCD-swizzled flat grid 1024: each XCD owns 4 (b,h) pairs -> K/V slab
// (2 MB) resident in that XCD's L2 across its 32 q-tiles.
// ---------------------------------------------------------------------------
__global__ __launch_bounds__(256) void attn_mfma(
    const u16* __restrict__ Qw, const u16* __restrict__ Kw,
    const u16* __restrict__ VwT, const int* __restrict__ mask,
    const int* __restrict__ tstat, u16* __restrict__ Aw)
{
    __shared__ __align__(16) u16 Ks [64][72];  // [c][d]  (144B stride)
    __shared__ __align__(16) u16 VsT[64][72];  // [d][c]
    __shared__ __align__(16) u16 Ps [64][72];  // [q-row][c], wave-private bands
    __shared__ int Msk[64];

    const int f = blockIdx.x;
    const int xcd = f & 7, q = f >> 3;          // q 0..127
    const int p = xcd * 4 + (q >> 5);           // (b,h) pair 0..31
    const int qt = q & 31;
    const int b = p >> 4, h = p & 15;
    const int q0 = qt * 64;

    const int t = threadIdx.x;
    const int lane = t & 63, wave = t >> 6;
    const int quad = lane >> 4, l15 = lane & 15;
    const bool use_mask = (tstat[0] != 0);
    const size_t slab = (size_t)(b * Hn + h) * Sn * DHn;

    // Preload Q A-frags (row = wave*16+l15, k-chunks ks*32 + quad*8)
    bf16x8 aq[2];
#pragma unroll
    for (int ks = 0; ks < 2; ks++) {
        union { uint4 u; bf16x8 v; } xx;
        xx.u = *(const uint4*)(Qw + slab + (size_t)(q0 + wave * 16 + l15) * DHn + ks * 32 + quad * 8);
        aq[ks] = xx.v;
    }

    float lsum[4] = {0.f, 0.f, 0.f, 0.f};
    f32x4 O[4];
#pragma unroll
    for (int dt = 0; dt < 4; dt++) O[dt] = (f32x4){0.f, 0.f, 0.f, 0.f};

    for (int j0 = 0; j0 < Sn; j0 += 64) {
        __syncthreads();  // (1) prior iteration's Ks/VsT reads complete
        {
            const int row = t >> 2, e0 = (t & 3) * 16;
#pragma unroll
            for (int hf = 0; hf < 2; hf++) {
                const int eo = e0 + hf * 8;
                const uint4 kv = *(const uint4*)(Kw  + slab + (size_t)(j0 + row) * DHn + eo);
                const uint4 vv = *(const uint4*)(VwT + slab + (size_t)row * Sn + j0 + eo);
                *(uint4*)&Ks [row][eo] = kv;
                *(uint4*)&VsT[row][eo] = vv;
            }
            if (t < 64) Msk[t] = use_mask ? mask[b * Sn + j0 + t] : 1;
        }
        __syncthreads();  // (2) staging visible

        // ---- S = Q K^T (D-layout: row=quad*4+r, col=ct*16+l15) ----
        f32x4 s[4];
#pragma unroll
        for (int ct = 0; ct < 4; ct++) s[ct] = (f32x4){0.f, 0.f, 0.f, 0.f};
#pragma unroll
        for (int ct = 0; ct < 4; ct++)
#pragma unroll
            for (int ks = 0; ks < 2; ks++) {
                const bf16x8 bk = ldfrag(&Ks[ct * 16 + l15][ks * 32 + quad * 8]);
                s[ct] = __builtin_amdgcn_mfma_f32_16x16x32_bf16(aq[ks], bk, s[ct], 0, 0, 0);
            }

        // ---- P = exp(mask ? s/64 : -1e9); accumulate l; stash P in LDS ----
        int mc[4];
#pragma unroll
        for (int ct = 0; ct < 4; ct++) mc[ct] = Msk[ct * 16 + l15];
#pragma unroll
        for (int ct = 0; ct < 4; ct++)
#pragma unroll
            for (int r = 0; r < 4; r++) {
                const float sv = mc[ct] ? s[ct][r] * (1.0f / 64.0f) : -1e9f;
                const float pp = __expf(sv);    // exp(-1e9) flushes to 0
                lsum[r] += pp;
                Ps[wave * 16 + quad * 4 + r][ct * 16 + l15] = f2bf(pp);
            }
        // Wave-private band; make the DS write->read hazard airtight:
        asm volatile("s_waitcnt lgkmcnt(0)" ::: "memory");

        // ---- O += P V ----
        bf16x8 pa[2];
#pragma unroll
        for (int kc = 0; kc < 2; kc++)
            pa[kc] = ldfrag(&Ps[wave * 16 + l15][kc * 32 + quad * 8]);
#pragma unroll
        for (int dt = 0; dt < 4; dt++)
#pragma unroll
            for (int kc = 0; kc < 2; kc++) {
                const bf16x8 bvv = ldfrag(&VsT[dt * 16 + l15][kc * 32 + quad * 8]);
                O[dt] = __builtin_amdgcn_mfma_f32_16x16x32_bf16(pa[kc], bvv, O[dt], 0, 0, 0);
            }
    }

    // ---- reduce l across the 16 column-lanes ----
#pragma unroll
    for (int r = 0; r < 4; r++) {
#pragma unroll
        for (int off = 1; off < 16; off <<= 1) lsum[r] += __shfl_xor(lsum[r], off);
    }

    // ---- epilogue: normalize, overwrite the Q slab ([b,h,s,d]) ----
#pragma unroll
    for (int r = 0; r < 4; r++) {
        const float linv = 1.0f / fmaxf(lsum[r], 1e-30f);
        const int srow = q0 + wave * 16 + quad * 4 + r;
#pragma unroll
        for (int dt = 0; dt < 4; dt++)
            Aw[slab + (size_t)srow * DHn + dt * 16 + l15] = f2bf(O[dt][r] * linv);
    }
}

// ---------------------------------------------------------------------------
extern "C" void kernel_launch(void* const* d_in, const int* in_sizes, int n_in,
                              void* d_out, int out_size, void* d_ws, size_t ws_size,
                              hipStream_t stream) {
    const float* query = (const float*)d_in[0];
    const float* key   = (const float*)d_in[1];
    const float* value = (const float*)d_in[2];
    const int*   pmask = (const int*)d_in[3];
    const int*   tstat = (const int*)d_in[4];
    const float* Wq  = (const float*)d_in[5];
    const float* bq  = (const float*)d_in[6];
    const float* Wk  = (const float*)d_in[7];
    const float* bk  = (const float*)d_in[8];
    const float* Wv  = (const float*)d_in[9];
    const float* bv  = (const float*)d_in[10];
    const float* Wf  = (const float*)d_in[11];
    const float* bfb = (const float*)d_in[12];
    float* outp = (float*)d_out;

    // ws (32 MB): Qw(8, attn-out alias) | Kw(8) | VwT(8) | Wt 4x2MB(8)
    const size_t NT = (size_t)Bn * Sn * DIMn;  // 4 Mi elements
    u16* Qw  = (u16*)d_ws;
    u16* Kw  = Qw + NT;
    u16* VwT = Kw + NT;
    u16* Wt  = VwT + NT;
    const size_t WSZ = (size_t)DIMn * DIMn;

    prep_weights<<<dim3(16, 16, 4), 256, 0, stream>>>(Wq, Wk, Wv, Wf, Wt);

    gemm_qkv<<<768, 256, 0, stream>>>(query, key, value, Wt, bq, bk, bv, Qw, Kw, VwT);

    attn_mfma<<<1024, 256, 0, stream>>>(Qw, Kw, VwT, pmask, tstat, Qw);

    gemm_final<<<256, 256, 0, stream>>>(Qw, Wt + 3 * WSZ, bfb, outp);
}

// Round 9
// 309.677 us; speedup vs baseline: 1.1730x; 1.1730x over previous
//
#include <hip/hip_runtime.h>

// Problem: B=2, S=2048, DIM=1024, H=16, DH=64. I/O fp32; internals bf16 MFMA.
#define Bn   2
#define Sn   2048
#define DIMn 1024
#define Hn   16
#define DHn  64

typedef unsigned short u16;
typedef unsigned int   u32;

typedef __attribute__((ext_vector_type(8))) __bf16 bf16x8;
typedef __attribute__((ext_vector_type(8))) float  f32x8v;
typedef __attribute__((ext_vector_type(4))) float  f32x4;

__device__ __forceinline__ u16 f2bf(float f) {
    union { float f; u32 u; } v; v.f = f;
    u32 r = v.u + 0x7fffu + ((v.u >> 16) & 1u);  // RNE
    return (u16)(r >> 16);
}
__device__ __forceinline__ bf16x8 ldfrag(const u16* p) {
    union { uint4 u; bf16x8 v; } x;
    x.u = *(const uint4*)p;
    return x.v;
}
__device__ __forceinline__ uint4 pack8(const u16 h[8]) {
    uint4 r;
    r.x = (u32)h[0] | ((u32)h[1] << 16);
    r.y = (u32)h[2] | ((u32)h[3] << 16);
    r.z = (u32)h[4] | ((u32)h[5] << 16);
    r.w = (u32)h[6] | ((u32)h[7] << 16);
    return r;
}
// async 16B global->LDS: lds dest = wave-uniform base + lane*16
__device__ __forceinline__ void gl_lds16(const void* g, void* l) {
    __builtin_amdgcn_global_load_lds(
        (const __attribute__((address_space(1))) void*)g,
        (__attribute__((address_space(3))) void*)l, 16, 0, 0);
}

// ---------------------------------------------------------------------------
// Prep: transpose+convert the 4 fp32 weights [k][n] -> bf16 Wt[n][k].
// ---------------------------------------------------------------------------
__global__ __launch_bounds__(256) void prep_weights(
    const float* __restrict__ Wq, const float* __restrict__ Wk,
    const float* __restrict__ Wv, const float* __restrict__ Wf,
    u16* __restrict__ Wt)
{
    __shared__ __align__(16) float tile[64][68];
    const float* W = (blockIdx.z == 0) ? Wq : (blockIdx.z == 1) ? Wk
                   : (blockIdx.z == 2) ? Wv : Wf;
    u16* out = Wt + (size_t)blockIdx.z * DIMn * DIMn;
    const int t = threadIdx.x;
    const int n0 = blockIdx.x * 64, k0 = blockIdx.y * 64;
    const int rr = t >> 4, cc = (t & 15) * 4;
#pragma unroll
    for (int i = 0; i < 4; i++)
        *(float4*)&tile[rr + 16 * i][cc] =
            *(const float4*)(W + (size_t)(k0 + rr + 16 * i) * DIMn + n0 + cc);
    __syncthreads();
#pragma unroll
    for (int e = 0; e < 2; e++) {
        const int ci = 2 * t + e;
        const int n = ci >> 3, kc = ci & 7;
        u16 h[8];
#pragma unroll
        for (int j = 0; j < 8; j++) h[j] = f2bf(tile[kc * 8 + j][n]);
        *(uint4*)(out + (size_t)(n0 + n) * DIMn + k0 + kc * 8) = pack8(h);
    }
}

// ---------------------------------------------------------------------------
// Fused QKV GEMM, global_load_lds staging, chunked LDS (lane-order layouts).
// A tile fp32 [128 x 32] as 64 chunks of 256B: chunk(g,q,h)=g*8+q*2+h holds
// rows g*16+l15, fp32 cols q*8+h*4..+4. B tile bf16 as 32 chunks:
// chunk(jg,q)=jg*4+q holds rows jg*16+l15, k cols q*8..+8.
// ---------------------------------------------------------------------------
__global__ __launch_bounds__(256) void gemm_qkv(
    const float* __restrict__ Aq, const float* __restrict__ Ak,
    const float* __restrict__ Av, const u16* __restrict__ Wt,
    const float* __restrict__ bqp, const float* __restrict__ bkp,
    const float* __restrict__ bvp, u16* __restrict__ Qw,
    u16* __restrict__ Kw, u16* __restrict__ VwT)
{
    __shared__ union {
        struct { __align__(16) float Afp[64 * 64];   // 16 KB, chunked
                 __align__(16) u16   Bbf[32 * 128]; } s;  // 8 KB, chunked
        __align__(16) u16 Ep[32][144];               // epilogue staging
    } L;

    // ---- XCD-aware swizzle: f = xcd + 8*(x + 8*(yi + 4*z)) ----
    const int f = blockIdx.x;
    const int xcd = f & 7;
    const int q = f >> 3;
    const int z = q >> 5;
    const int rem = q & 31;
    const int yi = rem >> 3, x = rem & 7;
    const int y = xcd * 4 + yi;
    const int m0 = y * 128, n0 = x * 128;

    const float* A    = (z == 0) ? Aq  : (z == 1) ? Ak  : Av;
    const float* bias = (z == 0) ? bqp : (z == 1) ? bkp : bvp;
    const u16* Bt = Wt + (size_t)z * DIMn * DIMn;

    const int t = threadIdx.x;
    const int lane = t & 63, wave = t >> 6;
    const int quad = lane >> 4, l15 = lane & 15;
    const int wm = wave >> 1, wn = wave & 1;

    // Per-s staging base pointers (k0-invariant part)
    const float* baseA[4];
#pragma unroll
    for (int s = 0; s < 4; s++) {
        const int c = wave * 16 + s * 4 + (lane >> 4);
        const int g = c >> 3, qq = (c >> 1) & 3, h = c & 1;
        baseA[s] = A + (size_t)(m0 + g * 16 + l15) * DIMn + qq * 8 + h * 4;
    }
    const u16* baseB[2];
#pragma unroll
    for (int s = 0; s < 2; s++) {
        const int c = wave * 8 + s * 4 + (lane >> 4);
        const int jg = c >> 2, qq = c & 3;
        baseB[s] = Bt + (size_t)(n0 + jg * 16 + l15) * DIMn + qq * 8;
    }

    f32x4 acc[4][4];
#pragma unroll
    for (int i = 0; i < 4; i++)
#pragma unroll
        for (int j = 0; j < 4; j++) acc[i][j] = (f32x4){0.f, 0.f, 0.f, 0.f};

    for (int k0 = 0; k0 < DIMn; k0 += 32) {
        __syncthreads();  // previous iteration's frag reads complete
#pragma unroll
        for (int s = 0; s < 4; s++)
            gl_lds16(baseA[s] + k0, &L.s.Afp[(wave * 16 + s * 4) * 64]);
#pragma unroll
        for (int s = 0; s < 2; s++)
            gl_lds16(baseB[s] + k0, &L.s.Bbf[(wave * 8 + s * 4) * 128]);
        __syncthreads();  // async loads drained (vmcnt) & visible

        bf16x8 a[4], b[4];
#pragma unroll
        for (int i = 0; i < 4; i++) {
            const int g = wm * 4 + i;
            union { struct { f32x4 lo, hi; } p; f32x8v v; } u;
            u.p.lo = *(const f32x4*)&L.s.Afp[(g * 8 + quad * 2 + 0) * 64 + l15 * 4];
            u.p.hi = *(const f32x4*)&L.s.Afp[(g * 8 + quad * 2 + 1) * 64 + l15 * 4];
            a[i] = __builtin_convertvector(u.v, bf16x8);
        }
#pragma unroll
        for (int j = 0; j < 4; j++)
            b[j] = ldfrag(&L.s.Bbf[((wn * 4 + j) * 4 + quad) * 128 + l15 * 8]);
#pragma unroll
        for (int i = 0; i < 4; i++)
#pragma unroll
            for (int j = 0; j < 4; j++)
                acc[i][j] = __builtin_amdgcn_mfma_f32_16x16x32_bf16(a[i], b[j], acc[i][j], 0, 0, 0);
    }

    float bv[4];
#pragma unroll
    for (int j = 0; j < 4; j++) bv[j] = bias[n0 + wn * 64 + j * 16 + l15];

    const int bb = y >> 4;

    if (z < 2) {
        // ---- split [b,h,s,d]: phase over i (32 m-rows x 128 n per phase) ----
        u16* out = (z == 0) ? Qw : Kw;
#pragma unroll
        for (int i = 0; i < 4; i++) {
            __syncthreads();
#pragma unroll
            for (int j = 0; j < 4; j++)
#pragma unroll
                for (int r = 0; r < 4; r++)
                    L.Ep[wm * 16 + quad * 4 + r][wn * 64 + j * 16 + l15] =
                        f2bf(acc[i][j][r] + bv[j]);
            __syncthreads();
#pragma unroll
            for (int e = 0; e < 2; e++) {
                const int ci = t + 256 * e;
                const int row = ci >> 4, c = ci & 15;
                const uint4 v = *(const uint4*)&L.Ep[row][c * 8];
                const int m = m0 + (row >> 4) * 64 + i * 16 + (row & 15);
                const int ss = m & 2047;
                const int n = n0 + c * 8;
                const int hh = n >> 6, dd = n & 63;
                *(uint4*)(out + ((size_t)(bb * Hn + hh) * Sn + ss) * DHn + dd) = v;
            }
        }
    } else {
        // ---- transposed [b,h,d,s]: phase over j (32 n-rows x 128 m) ----
#pragma unroll
        for (int j = 0; j < 4; j++) {
            __syncthreads();
#pragma unroll
            for (int i = 0; i < 4; i++) {
                u16 h4[4];
#pragma unroll
                for (int r = 0; r < 4; r++) h4[r] = f2bf(acc[i][j][r] + bv[j]);
                uint2 pk;
                pk.x = (u32)h4[0] | ((u32)h4[1] << 16);
                pk.y = (u32)h4[2] | ((u32)h4[3] << 16);
                *(uint2*)&L.Ep[wn * 16 + l15][wm * 64 + i * 16 + quad * 4] = pk;
            }
            __syncthreads();
#pragma unroll
            for (int e = 0; e < 2; e++) {
                const int ci = t + 256 * e;
                const int row = ci >> 4, c = ci & 15;
                const uint4 v = *(const uint4*)&L.Ep[row][c * 8];
                const int n = n0 + (row >> 4) * 64 + j * 16 + (row & 15);
                const int hh = n >> 6, dd = n & 63;
                const int ss = (m0 & 2047) + c * 8;
                *(uint4*)(VwT + ((size_t)(bb * Hn + hh) * DHn + dd) * Sn + ss) = v;
            }
        }
    }
}

// ---------------------------------------------------------------------------
// Final GEMM: A(bf16 split [b,h,s,d]) @ Wf + bias -> fp32 [m][n].
// Both tiles via global_load_lds, chunked LDS (32 chunks each).
// ---------------------------------------------------------------------------
__global__ __launch_bounds__(256) void gemm_final(
    const u16* __restrict__ A, const u16* __restrict__ Bt,
    const float* __restrict__ bias, float* __restrict__ out)
{
    __shared__ __align__(16) u16 Abf[32 * 128];  // 8 KB chunked
    __shared__ __align__(16) u16 Bbf[32 * 128];  // 8 KB chunked

    const int f = blockIdx.x;
    const int xcd = f & 7, q = f >> 3;
    const int y = xcd * 4 + (q >> 3), x = q & 7;
    const int m0 = y * 128, n0 = x * 128;

    const int t = threadIdx.x;
    const int lane = t & 63, wave = t >> 6;
    const int quad = lane >> 4, l15 = lane & 15;
    const int wm = wave >> 1, wn = wave & 1;

    // A staging decode (k0-dependent head): chunk c = g*4+qq
    int arow[2], aq[2];
#pragma unroll
    for (int s = 0; s < 2; s++) {
        const int c = wave * 8 + s * 4 + (lane >> 4);
        arow[s] = (c >> 2) * 16 + l15;  // local m row
        aq[s] = c & 3;
    }
    const u16* baseB[2];
#pragma unroll
    for (int s = 0; s < 2; s++) {
        const int c = wave * 8 + s * 4 + (lane >> 4);
        baseB[s] = Bt + (size_t)(n0 + (c >> 2) * 16 + l15) * DIMn + (c & 3) * 8;
    }

    f32x4 acc[4][4];
#pragma unroll
    for (int i = 0; i < 4; i++)
#pragma unroll
        for (int j = 0; j < 4; j++) acc[i][j] = (f32x4){0.f, 0.f, 0.f, 0.f};

    for (int k0 = 0; k0 < DIMn; k0 += 32) {
        const int hh = k0 >> 6, d64 = k0 & 63;
        __syncthreads();
#pragma unroll
        for (int s = 0; s < 2; s++) {
            const int m = m0 + arow[s], bb = m >> 11, ss = m & 2047;
            const u16* gp = A + ((size_t)(bb * Hn + hh) * Sn + ss) * DHn + d64 + aq[s] * 8;
            gl_lds16(gp, &Abf[(wave * 8 + s * 4) * 128]);
        }
#pragma unroll
        for (int s = 0; s < 2; s++)
            gl_lds16(baseB[s] + k0, &Bbf[(wave * 8 + s * 4) * 128]);
        __syncthreads();

        bf16x8 a[4], b[4];
#pragma unroll
        for (int i = 0; i < 4; i++)
            a[i] = ldfrag(&Abf[((wm * 4 + i) * 4 + quad) * 128 + l15 * 8]);
#pragma unroll
        for (int j = 0; j < 4; j++)
            b[j] = ldfrag(&Bbf[((wn * 4 + j) * 4 + quad) * 128 + l15 * 8]);
#pragma unroll
        for (int i = 0; i < 4; i++)
#pragma unroll
            for (int j = 0; j < 4; j++)
                acc[i][j] = __builtin_amdgcn_mfma_f32_16x16x32_bf16(a[i], b[j], acc[i][j], 0, 0, 0);
    }

    float bv[4];
#pragma unroll
    for (int j = 0; j < 4; j++) bv[j] = bias[n0 + wn * 64 + j * 16 + l15];

#pragma unroll
    for (int i = 0; i < 4; i++)
#pragma unroll
        for (int j = 0; j < 4; j++) {
            const int n = n0 + wn * 64 + j * 16 + l15;
#pragma unroll
            for (int r = 0; r < 4; r++) {
                const int m = m0 + wm * 64 + i * 16 + quad * 4 + r;
                out[(size_t)m * DIMn + n] = acc[i][j][r] + bv[j];
            }
        }
}

// ---------------------------------------------------------------------------
// MFMA flash attention (no max-tracking), global_load_lds K/V staging.
// K chunks: chunk(cg,q')=cg*8+q' holds key rows cg*16+l15, d cols q'*8..+8.
// V chunks: chunk(dg,q')=dg*8+q' holds d rows dg*16+l15, key cols q'*8..+8.
// ---------------------------------------------------------------------------
__global__ __launch_bounds__(256) void attn_mfma(
    const u16* __restrict__ Qw, const u16* __restrict__ Kw,
    const u16* __restrict__ VwT, const int* __restrict__ mask,
    const int* __restrict__ tstat, u16* __restrict__ Aw)
{
    __shared__ __align__(16) u16 Kbf[32 * 128];  // 8 KB chunked
    __shared__ __align__(16) u16 Vbf[32 * 128];  // 8 KB chunked
    __shared__ __align__(16) u16 Ps[64][72];     // P, wave-private bands
    __shared__ int Msk[64];

    const int f = blockIdx.x;
    const int xcd = f & 7, q = f >> 3;
    const int p = xcd * 4 + (q >> 5);
    const int qt = q & 31;
    const int b = p >> 4, h = p & 15;
    const int q0 = qt * 64;

    const int t = threadIdx.x;
    const int lane = t & 63, wave = t >> 6;
    const int quad = lane >> 4, l15 = lane & 15;
    const bool use_mask = (tstat[0] != 0);
    const size_t slab = (size_t)(b * Hn + h) * Sn * DHn;

    // Staging base pointers (j0-invariant parts)
    const u16* baseK[2];
    const u16* baseV[2];
#pragma unroll
    for (int s = 0; s < 2; s++) {
        const int c = wave * 8 + s * 4 + (lane >> 4);
        const int rg = c >> 3, qp = c & 7;
        baseK[s] = Kw  + slab + (size_t)(rg * 16 + l15) * DHn + qp * 8;  // + j0*DHn
        baseV[s] = VwT + slab + (size_t)(rg * 16 + l15) * Sn  + qp * 8;  // + j0
    }

    // Preload Q A-frags
    bf16x8 aq[2];
#pragma unroll
    for (int ks = 0; ks < 2; ks++) {
        union { uint4 u; bf16x8 v; } xx;
        xx.u = *(const uint4*)(Qw + slab + (size_t)(q0 + wave * 16 + l15) * DHn + ks * 32 + quad * 8);
        aq[ks] = xx.v;
    }

    float lsum[4] = {0.f, 0.f, 0.f, 0.f};
    f32x4 O[4];
#pragma unroll
    for (int dt = 0; dt < 4; dt++) O[dt] = (f32x4){0.f, 0.f, 0.f, 0.f};

    for (int j0 = 0; j0 < Sn; j0 += 64) {
        __syncthreads();  // prior iteration's reads complete
#pragma unroll
        for (int s = 0; s < 2; s++) {
            gl_lds16(baseK[s] + (size_t)j0 * DHn, &Kbf[(wave * 8 + s * 4) * 128]);
            gl_lds16(baseV[s] + j0,               &Vbf[(wave * 8 + s * 4) * 128]);
        }
        if (t < 64) Msk[t] = use_mask ? mask[b * Sn + j0 + t] : 1;
        __syncthreads();  // staging drained & visible

        // ---- S = Q K^T ----
        f32x4 s[4];
#pragma unroll
        for (int ct = 0; ct < 4; ct++) s[ct] = (f32x4){0.f, 0.f, 0.f, 0.f};
#pragma unroll
        for (int ct = 0; ct < 4; ct++)
#pragma unroll
            for (int ks = 0; ks < 2; ks++) {
                const bf16x8 bk = ldfrag(&Kbf[(ct * 8 + ks * 4 + quad) * 128 + l15 * 8]);
                s[ct] = __builtin_amdgcn_mfma_f32_16x16x32_bf16(aq[ks], bk, s[ct], 0, 0, 0);
            }

        // ---- P = exp(mask ? s/64 : -1e9); accumulate l; stash P ----
        int mc[4];
#pragma unroll
        for (int ct = 0; ct < 4; ct++) mc[ct] = Msk[ct * 16 + l15];
#pragma unroll
        for (int ct = 0; ct < 4; ct++)
#pragma unroll
            for (int r = 0; r < 4; r++) {
                const float sv = mc[ct] ? s[ct][r] * (1.0f / 64.0f) : -1e9f;
                const float pp = __expf(sv);
                lsum[r] += pp;
                Ps[wave * 16 + quad * 4 + r][ct * 16 + l15] = f2bf(pp);
            }
        asm volatile("s_waitcnt lgkmcnt(0)" ::: "memory");  // wave-private band

        // ---- O += P V ----
        bf16x8 pa[2];
#pragma unroll
        for (int kc = 0; kc < 2; kc++)
            pa[kc] = ldfrag(&Ps[wave * 16 + l15][kc * 32 + quad * 8]);
#pragma unroll
        for (int dt = 0; dt < 4; dt++)
#pragma unroll
            for (int kc = 0; kc < 2; kc++) {
                const bf16x8 bvv = ldfrag(&Vbf[(dt * 8 + kc * 4 + quad) * 128 + l15 * 8]);
                O[dt] = __builtin_amdgcn_mfma_f32_16x16x32_bf16(pa[kc], bvv, O[dt], 0, 0, 0);
            }
    }

    // ---- reduce l across the 16 column-lanes ----
#pragma unroll
    for (int r = 0; r < 4; r++) {
#pragma unroll
        for (int off = 1; off < 16; off <<= 1) lsum[r] += __shfl_xor(lsum[r], off);
    }

    // ---- epilogue: normalize, overwrite the Q slab ([b,h,s,d]) ----
#pragma unroll
    for (int r = 0; r < 4; r++) {
        const float linv = 1.0f / fmaxf(lsum[r], 1e-30f);
        const int srow = q0 + wave * 16 + quad * 4 + r;
#pragma unroll
        for (int dt = 0; dt < 4; dt++)
            Aw[slab + (size_t)srow * DHn + dt * 16 + l15] = f2bf(O[dt][r] * linv);
    }
}

// ---------------------------------------------------------------------------
extern "C" void kernel_launch(void* const* d_in, const int* in_sizes, int n_in,
                              void* d_out, int out_size, void* d_ws, size_t ws_size,
                              hipStream_t stream) {
    const float* query = (const float*)d_in[0];
    const float* key   = (const float*)d_in[1];
    const float* value = (const float*)d_in[2];
    const int*   pmask = (const int*)d_in[3];
    const int*   tstat = (const int*)d_in[4];
    const float* Wq  = (const float*)d_in[5];
    const float* bq  = (const float*)d_in[6];
    const float* Wk  = (const float*)d_in[7];
    const float* bk  = (const float*)d_in[8];
    const float* Wv  = (const float*)d_in[9];
    const float* bv  = (const float*)d_in[10];
    const float* Wf  = (const float*)d_in[11];
    const float* bfb = (const float*)d_in[12];
    float* outp = (float*)d_out;

    // ws (32 MB): Qw(8, attn-out alias) | Kw(8) | VwT(8) | Wt 4x2MB(8)
    const size_t NT = (size_t)Bn * Sn * DIMn;
    u16* Qw  = (u16*)d_ws;
    u16* Kw  = Qw + NT;
    u16* VwT = Kw + NT;
    u16* Wt  = VwT + NT;
    const size_t WSZ = (size_t)DIMn * DIMn;

    prep_weights<<<dim3(16, 16, 4), 256, 0, stream>>>(Wq, Wk, Wv, Wf, Wt);

    gemm_qkv<<<768, 256, 0, stream>>>(query, key, value, Wt, bq, bk, bv, Qw, Kw, VwT);

    attn_mfma<<<1024, 256, 0, stream>>>(Qw, Kw, VwT, pmask, tstat, Qw);

    gemm_final<<<256, 256, 0, stream>>>(Qw, Wt + 3 * WSZ, bfb, outp);
}